// Round 23
// baseline (403.323 us; speedup 1.0000x reference)
//
#include <hip/hip_runtime.h>
#include <hip/hip_bf16.h>

typedef unsigned long long ull;

// ---------------- problem constants ----------------
constexpr int BATCH = 8;
constexpr int NA    = 261888;
constexpr int KSEL  = 6000;          // PRE_NMS_LIMIT
constexpr int PROP  = 1000;          // PROPOSAL_COUNT
constexpr int CAP   = 8192;          // candidate capacity
constexpr int NBINS = 8192;          // histogram bins
constexpr int HB    = 16;            // private histogram blocks per batch
constexpr int NB    = (KSEL + 63) / 64;   // 94 mask words per row
constexpr int NWP   = 94;            // words per row (752B rows)
constexpr int NBLK  = 94;            // row-blocks

// workspace layout (bytes). keys/rank/hist alias the mask head (disjoint liveness).
constexpr size_t OFF_CNT   = 0;                       // 512
constexpr size_t OFF_TSEL  = 512;                     // 32
constexpr size_t OFF_BOXES = 544;                     // 8*6000*16 = 768000
constexpr size_t OFF_MASK  = 769024;                  // 8*6000*94*8 = 36096000
constexpr size_t OFF_DIAG  = OFF_MASK + 36096000;     // 8*94*64*8 = 385024
constexpr size_t OFF_SUP   = OFF_DIAG + 385024;       // 8*94*64*8 = 385024
constexpr size_t OFF_KEYS  = OFF_MASK;                // aliased
constexpr size_t OFF_RANK  = OFF_MASK + 524288;       // aliased
constexpr size_t OFF_HIST  = OFF_MASK + 2097152;      // aliased
// total = 37,635,072 B

__device__ __forceinline__ int score_bin(float s) {
  int b = (int)(s * (float)NBINS);
  if (b < 0) b = 0;
  if (b > NBINS - 1) b = NBINS - 1;
  return b;
}

__device__ __forceinline__ float bcast(float v, int r) {
  return __int_as_float(__builtin_amdgcn_readlane(__float_as_int(v), r));
}

// ---------------- 1. histogram ----------------
__global__ __launch_bounds__(256) void hist_kernel(const float2* __restrict__ probs,
                                                   unsigned int* __restrict__ hist) {
  __shared__ unsigned int lh[NBINS];
  for (int i = threadIdx.x; i < NBINS; i += 256) lh[i] = 0u;
  __syncthreads();
  int b = blockIdx.y;
  const float2* p = probs + (size_t)b * NA;
  for (int a = blockIdx.x * 256 + threadIdx.x; a < NA; a += HB * 256) {
    atomicAdd(&lh[score_bin(p[a].y)], 1u);
  }
  __syncthreads();
  unsigned int* gh = hist + ((size_t)b * HB + blockIdx.x) * NBINS;
  for (int i = threadIdx.x; i < NBINS; i += 256) gh[i] = lh[i];
}

// ---------------- 2. threshold bin select ----------------
__global__ __launch_bounds__(256) void thresh_kernel(const unsigned int* __restrict__ hist,
                                                     int* __restrict__ tsel) {
  constexpr int GR = NBINS / 256;
  __shared__ unsigned int ch[NBINS];
  __shared__ unsigned int gsum[256];
  int b = blockIdx.x;
  const unsigned int* h = hist + (size_t)b * HB * NBINS;
  for (int bin = threadIdx.x; bin < NBINS; bin += 256) {
    unsigned int s = 0;
    for (int k = 0; k < HB; ++k) s += h[(size_t)k * NBINS + bin];
    ch[bin] = s;
  }
  __syncthreads();
  unsigned int s = 0;
  int g0 = threadIdx.x * GR;
  for (int i = 0; i < GR; ++i) s += ch[g0 + i];
  gsum[threadIdx.x] = s;
  __syncthreads();
  if (threadIdx.x == 0) {
    unsigned int acc = 0;
    int g = 255;
    for (; g > 0; --g) {
      if (acc + gsum[g] >= (unsigned)KSEL) break;
      acc += gsum[g];
    }
    int t = g * GR;
    for (int bin = g * GR + GR - 1; bin >= g * GR; --bin) {
      acc += ch[bin];
      if (acc >= (unsigned)KSEL) { t = bin; break; }
    }
    tsel[b] = t;
  }
}

// ---------------- 3. compact candidates ----------------
__global__ __launch_bounds__(256) void compact_kernel(const float2* __restrict__ probs,
                                                      const int* __restrict__ tsel,
                                                      int* __restrict__ cnt,
                                                      ull* __restrict__ keys) {
  __shared__ int lcnt, lbase;
  __shared__ ull lbuf[2048];
  int b = blockIdx.y;
  int t = tsel[b];
  if (threadIdx.x == 0) lcnt = 0;
  __syncthreads();
  const float2* p = probs + (size_t)b * NA;
  for (int a = blockIdx.x * blockDim.x + threadIdx.x; a < NA; a += gridDim.x * blockDim.x) {
    float s = p[a].y;
    if (score_bin(s) >= t) {
      int pos = atomicAdd(&lcnt, 1);
      unsigned int ib = ~__float_as_uint(s);
      lbuf[pos] = ((ull)ib << 32) | (unsigned int)a;
    }
  }
  __syncthreads();
  if (threadIdx.x == 0) lbase = atomicAdd(&cnt[b * 16], lcnt);
  __syncthreads();
  int n = lcnt, base = lbase;
  ull* kb = keys + (size_t)b * CAP;
  for (int i = threadIdx.x; i < n; i += 256) {
    int pos = base + i;
    if (pos < CAP) kb[pos] = lbuf[i];
  }
}

// ---------------- 4a. rank by counting ----------------
__global__ __launch_bounds__(256) void rank_kernel(const int* __restrict__ cnt,
                                                   const ull* __restrict__ keys,
                                                   unsigned int* __restrict__ rank) {
  int b = blockIdx.z;
  int n = cnt[b * 16];
  if (n > CAP) n = CAP;
  int i = blockIdx.x * 256 + threadIdx.x;
  if (i >= n) return;
  const ull* kb = keys + (size_t)b * CAP;
  ull my = kb[i];
  int n16 = (n + 15) & ~15;
  int nchunks = n16 >> 4;
  int hc = nchunks >> 1;
  int jlo = (blockIdx.y == 0) ? 0 : hc * 16;
  int jhi = (blockIdx.y == 0) ? hc * 16 : n16;
  unsigned int r = 0;
  for (int j = jlo; j < jhi; j += 16) {
#pragma unroll
    for (int t = 0; t < 16; ++t) {
      r += (kb[j + t] < my) ? 1u : 0u;
    }
  }
  if (r) atomicAdd(&rank[(size_t)b * CAP + i], r);
}

// ---------------- 4b. scatter + box decode ----------------
__global__ __launch_bounds__(256) void scatter_kernel(const float4* __restrict__ anchors4,
                                                      const float4* __restrict__ bbox4,
                                                      const int* __restrict__ cnt,
                                                      const ull* __restrict__ keys,
                                                      const unsigned int* __restrict__ rank,
                                                      float4* __restrict__ boxes4) {
#pragma clang fp contract(off)
  int b = blockIdx.y;
  int n = cnt[b * 16];
  if (n > CAP) n = CAP;
  int i = blockIdx.x * 256 + threadIdx.x;
  if (i >= n) return;
  unsigned int r = rank[(size_t)b * CAP + i];
  if (r >= (unsigned)KSEL) return;
  int a = (int)(unsigned int)(keys[(size_t)b * CAP + i] & 0xffffffffull);
  float4 anc = anchors4[(size_t)b * NA + a];
  float4 d   = bbox4[(size_t)b * NA + a];
  float h = anc.z - anc.x;
  float w = anc.w - anc.y;
  float dy = d.x * 0.1f, dx = d.y * 0.1f, dh = d.z * 0.2f, dw = d.w * 0.2f;
  float cy = (anc.x + (0.5f * h)) + (dy * h);
  float cx = (anc.y + (0.5f * w)) + (dx * w);
  float h2 = h * expf(dh);
  float w2 = w * expf(dw);
  float y1 = cy - 0.5f * h2;
  float x1 = cx - 0.5f * w2;
  float y2 = y1 + h2;
  float x2 = x1 + w2;
  y1 = fminf(fmaxf(y1, 0.f), 1.f);
  x1 = fminf(fmaxf(x1, 0.f), 1.f);
  y2 = fminf(fmaxf(y2, 0.f), 1.f);
  x2 = fminf(fmaxf(x2, 0.f), 1.f);
  boxes4[(size_t)b * KSEL + r] = make_float4(y1, x1, y2, x2);
}

// ---------------- 5. suppression mask: ballot-built words (lane = column) ----------------
// grid (24, 94, 8). Block owns rows rb*64..+63; wave wv computes word cb = rb+4*cx+wv.
// Column boxes in REGISTERS (loaded once); per row r: 5 readlane broadcasts + lane-parallel
// IoU + ONE __ballot => the 64-bit word. No per-pair 64-bit shifts, no hot-loop LDS.
// diagT written col-form via ballot transpose; superT row-form (word rb+1 of block-rb rows).
__global__ __launch_bounds__(256) void mask_kernel(const float4* __restrict__ boxes4,
                                                   ull* __restrict__ mask,
                                                   ull* __restrict__ diagT,
                                                   ull* __restrict__ superT) {
#pragma clang fp contract(off)
  int cx = blockIdx.x, rb = blockIdx.y, b = blockIdx.z;
  int cb0 = rb + 4 * cx;
  if (cb0 >= NWP) return;
  __shared__ ull wtile[64][5];
  int tid = threadIdx.x, wv = tid >> 6, l = tid & 63;
  int cb = cb0 + wv;
  float4 zero = make_float4(0.f, 0.f, 0.f, 0.f);
  int row = rb * 64 + l;
  float4 rbox = (row < KSEL) ? boxes4[(size_t)b * KSEL + row] : zero;
  float rarea = (rbox.z - rbox.x) * (rbox.w - rbox.y);
  bool vcb = (cb < NB);
  int c = cb * 64 + l;
  float4 cbox = (vcb && c < KSEL) ? boxes4[(size_t)b * KSEL + c] : zero;
  float ca = (cbox.z - cbox.x) * (cbox.w - cbox.y);
  ull myword = 0ull;
  if (vcb) {
    bool isdiag = (cb == rb);
#pragma unroll
    for (int r = 0; r < 64; ++r) {
      float ry1 = bcast(rbox.x, r);
      float rx1 = bcast(rbox.y, r);
      float ry2 = bcast(rbox.z, r);
      float rx2 = bcast(rbox.w, r);
      float rA  = bcast(rarea,  r);
      float ih = fmaxf(fminf(ry2, cbox.z) - fmaxf(ry1, cbox.x), 0.f);
      float iw = fmaxf(fminf(rx2, cbox.w) - fmaxf(rx1, cbox.y), 0.f);
      float inter = ih * iw;
      float uni = (rA + ca) - inter;
      float d = fmaf(-0.7f, uni, inter);
      float tt = 6e-7f * uni;
      bool keep;
      if (__builtin_fabsf(d) <= tt) {
        keep = (inter / uni) > 0.7f;   // exact tie path (rare; 0/0 -> NaN -> false)
      } else {
        keep = d > 0.f;
      }
      ull bits = __ballot(keep);
      if (isdiag) bits &= (r == 63) ? 0ull : (~0ull << (r + 1)); // only cc > row
      if (l == r) myword = bits;
    }
    if (isdiag) {
      // ballot transpose: colT[l] bit r = bit l of row-word r
      ull colT = 0ull;
#pragma unroll
      for (int k = 0; k < 64; ++k) {
        ull bk = __ballot(((myword >> k) & 1ull) != 0ull);
        if (l == k) colT = bk;
      }
      diagT[((size_t)b * NBLK + rb) * 64 + l] = colT;
    }
    if (cb == rb + 1) {
      superT[((size_t)b * NBLK + rb) * 64 + l] = myword; // word rb+1 of block-rb rows
    }
  }
  wtile[l][wv] = myword;
  __syncthreads();
  // coalesced flush: 64 rows x 4 words
  int rr = tid >> 2, w = tid & 3;
  int orow = rb * 64 + rr;
  if (orow < KSEL && cb0 + w < NWP)
    mask[((size_t)b * KSEL + orow) * NWP + cb0 + w] = wtile[rr][w];
}

// ---------------- 6. scan: ballot decision + urgent superdiag + concurrent lazy OR ----------------
__global__ __launch_bounds__(256, 1) void scan_kernel(const float4* __restrict__ boxes4,
                                                      const ull* __restrict__ mask,
                                                      const ull* __restrict__ diagT,
                                                      const ull* __restrict__ superT,
                                                      float4* __restrict__ out4) {
  __shared__ ull ldiagT[NBLK * 64];  // column form
  __shared__ ull lsuper[NBLK * 64];  // row form
  __shared__ ull S[96];
  __shared__ ull S_urg;
  __shared__ int klist[2][64];
  __shared__ int skeep[1024];
  __shared__ int s_kept, s_done, s_klen[2];
  int b = blockIdx.x;
  int tid = threadIdx.x;
  int lane = tid & 63;
  const ull* mb = mask + (size_t)b * KSEL * NWP;

  const ull* dt = diagT + (size_t)b * NBLK * 64;
  const ull* st = superT + (size_t)b * NBLK * 64;
  for (int i = tid; i < NBLK * 64; i += 256) { ldiagT[i] = dt[i]; lsuper[i] = st[i]; }
  if (tid < 96) S[tid] = 0ull;
  if (tid == 0) { s_kept = 0; s_done = 0; s_klen[0] = 0; s_klen[1] = 0; S_urg = 0ull; }
  __syncthreads();

  for (int n = 0; n < NBLK; ++n) {
    if (tid < 64) {
      ull Sn = S[n] | S_urg;
      int i0 = n * 64;
      ull colT = ldiagT[i0 + lane];
      ull sd = (n + 1 < NBLK) ? lsuper[i0 + lane] : 0ull;
      int nval = KSEL - i0;
      ull valid = (nval >= 64) ? ~0ull : ((1ull << nval) - 1ull);
      ull A = ~Sn & valid;
      ull K = 0ull;
      int kept = s_kept;
      int done = 0;
      while (A) {
        int u = __builtin_ctzll(A);
        ++kept;
        K |= (1ull << u);
        if (kept >= PROP) { done = 1; break; }
        ull sup = __ballot(((colT >> u) & 1ull) != 0ull);
        A &= ~(sup | (1ull << u));
      }
      int klen = __builtin_popcountll(K);
      int kbase = kept - klen;
      if ((K >> lane) & 1ull) {
        int rank = __builtin_popcountll(K & ((1ull << lane) - 1ull));
        skeep[kbase + rank] = i0 + lane;
        klist[n & 1][rank] = i0 + lane;
      }
      int klp = (klen + 7) & ~7;
      if (klen > 0 && lane >= klen && lane < klp)
        klist[n & 1][lane] = i0 + __builtin_ctzll(K);
      unsigned ulo = (unsigned)sd, uhi = (unsigned)(sd >> 32);
      if (!((K >> lane) & 1ull)) { ulo = 0u; uhi = 0u; }
#pragma unroll
      for (int m = 1; m < 64; m <<= 1) {
        ulo |= (unsigned)__shfl_xor((int)ulo, m, 64);
        uhi |= (unsigned)__shfl_xor((int)uhi, m, 64);
      }
      if (lane == 0) {
        s_klen[n & 1] = klen;
        S_urg = (ull)ulo | ((ull)uhi << 32);
        s_kept = kept;
        if (done || n == NBLK - 1) s_done = 1;
      }
    } else {
      int prev = (n & 1) ^ 1;
      int kl = s_klen[prev];
      int w = n + 1 + (tid - 64);
      if (kl > 0 && w < NB) {
        const int* kp = klist[prev];
        ull acc = 0ull;
        int klp = (kl + 7) & ~7;
        for (int ri = 0; ri < klp; ri += 8) {
#pragma unroll
          for (int t2 = 0; t2 < 8; ++t2)
            acc |= mb[(size_t)kp[ri + t2] * NWP + w];
        }
        S[w] |= acc;
      }
    }
    __syncthreads();
    if (s_done) break;
  }

  int fin = s_kept;
  if (fin > PROP) fin = PROP;
  for (int r2 = tid; r2 < PROP; r2 += 256) {
    float4 v = make_float4(0.f, 0.f, 0.f, 0.f);
    if (r2 < fin) v = boxes4[(size_t)b * KSEL + skeep[r2]];
    out4[(size_t)b * PROP + r2] = v;
  }
}

// ---------------- launch ----------------
extern "C" void kernel_launch(void* const* d_in, const int* in_sizes, int n_in,
                              void* d_out, int out_size, void* d_ws, size_t ws_size,
                              hipStream_t stream) {
  const float2* probs   = (const float2*)d_in[0];
  const float4* bbox4   = (const float4*)d_in[1];
  const float4* anchors4= (const float4*)d_in[2];
  float4* out4 = (float4*)d_out;
  char* ws = (char*)d_ws;

  int* cnt           = (int*)(ws + OFF_CNT);
  int* tsel          = (int*)(ws + OFF_TSEL);
  float4* boxes4     = (float4*)(ws + OFF_BOXES);
  ull* maskw         = (ull*)(ws + OFF_MASK);
  ull* diagT         = (ull*)(ws + OFF_DIAG);
  ull* superT        = (ull*)(ws + OFF_SUP);
  ull* keys          = (ull*)(ws + OFF_KEYS);
  unsigned int* rank = (unsigned int*)(ws + OFF_RANK);
  unsigned int* hist = (unsigned int*)(ws + OFF_HIST);

  hipMemsetAsync(ws + OFF_CNT, 0, 544, stream);
  hipMemsetAsync(ws + OFF_KEYS, 0xFF, 524288, stream);
  hipMemsetAsync(ws + OFF_RANK, 0, 262144, stream);

  hipLaunchKernelGGL(hist_kernel,    dim3(HB, BATCH),      dim3(256), 0, stream, probs, hist);
  hipLaunchKernelGGL(thresh_kernel,  dim3(BATCH),          dim3(256), 0, stream, hist, tsel);
  hipLaunchKernelGGL(compact_kernel, dim3(128, BATCH),     dim3(256), 0, stream, probs, tsel, cnt, keys);
  hipLaunchKernelGGL(rank_kernel,    dim3(32, 2, BATCH),   dim3(256), 0, stream, cnt, keys, rank);
  hipLaunchKernelGGL(scatter_kernel, dim3(32, BATCH),      dim3(256), 0, stream, anchors4, bbox4, cnt, keys, rank, boxes4);
  hipLaunchKernelGGL(mask_kernel,    dim3(24, NBLK, BATCH), dim3(256), 0, stream, boxes4, maskw, diagT, superT);
  hipLaunchKernelGGL(scan_kernel,    dim3(BATCH),          dim3(256), 0, stream, boxes4, maskw, diagT, superT, out4);
}

// Round 24
// 391.149 us; speedup vs baseline: 1.0311x; 1.0311x over previous
//
#include <hip/hip_runtime.h>
#include <hip/hip_bf16.h>

typedef unsigned long long ull;

// ---------------- problem constants ----------------
constexpr int BATCH = 8;
constexpr int NA    = 261888;
constexpr int KSEL  = 6000;          // PRE_NMS_LIMIT
constexpr int PROP  = 1000;          // PROPOSAL_COUNT
constexpr int CAP   = 8192;          // candidate capacity
constexpr int NBINS = 8192;          // histogram bins
constexpr int HB    = 16;            // private histogram blocks per batch
constexpr int NB    = (KSEL + 63) / 64;   // 94 mask words per row
constexpr int NWP   = 94;            // words per row (752B rows)
constexpr int NBLK  = 94;            // row-blocks
constexpr int NBLK2 = 47;            // 128-row pair-blocks (mask kernel)

// workspace layout (bytes). keys/hist alias the mask head (disjoint liveness).
constexpr size_t OFF_CNT   = 0;                       // 512 (128 ints)
constexpr size_t OFF_TSEL  = 512;                     // 32
constexpr size_t OFF_BOXES = 544;                     // 8*6000*16 = 768000
constexpr size_t OFF_MASK  = 769024;                  // 8*6000*94*8 = 36096000
constexpr size_t OFF_DIAG  = OFF_MASK + 36096000;     // 8*94*64*8 = 385024
constexpr size_t OFF_SUP   = OFF_DIAG + 385024;       // 8*94*64*8 = 385024
constexpr size_t OFF_KEYS  = OFF_MASK;                // 524288 (aliased)
constexpr size_t OFF_HIST  = OFF_MASK + 2097152;      // 4MB (aliased)
// total = 37,635,072 B

__device__ __forceinline__ int score_bin(float s) {
  int b = (int)(s * (float)NBINS);
  if (b < 0) b = 0;
  if (b > NBINS - 1) b = NBINS - 1;
  return b;
}

// ---------------- 1. histogram (+ workspace init: cnt zero, keys 0xFF pad) ----------------
__global__ __launch_bounds__(256) void hist_kernel(const float2* __restrict__ probs,
                                                   unsigned int* __restrict__ hist,
                                                   int* __restrict__ cnt,
                                                   ull* __restrict__ keys) {
  __shared__ unsigned int lh[NBINS];
  for (int i = threadIdx.x; i < NBINS; i += 256) lh[i] = 0u;
  // fold in the init formerly done by 3 hipMemsetAsync (hist finishes before compact)
  int fb = blockIdx.y * HB + blockIdx.x;   // 0..127
  if (threadIdx.x == 0) cnt[fb] = 0;
  {
    ull* kp = keys + (size_t)fb * 512;     // 128 blocks x 512 = 65536 ull = whole keys region
    for (int i = threadIdx.x; i < 512; i += 256) kp[i] = ~0ull;
  }
  __syncthreads();
  int b = blockIdx.y;
  const float2* p = probs + (size_t)b * NA;
  for (int a = blockIdx.x * 256 + threadIdx.x; a < NA; a += HB * 256) {
    atomicAdd(&lh[score_bin(p[a].y)], 1u);
  }
  __syncthreads();
  unsigned int* gh = hist + ((size_t)b * HB + blockIdx.x) * NBINS;
  for (int i = threadIdx.x; i < NBINS; i += 256) gh[i] = lh[i];
}

// ---------------- 2. threshold bin select ----------------
__global__ __launch_bounds__(256) void thresh_kernel(const unsigned int* __restrict__ hist,
                                                     int* __restrict__ tsel) {
  constexpr int GR = NBINS / 256;
  __shared__ unsigned int ch[NBINS];
  __shared__ unsigned int gsum[256];
  int b = blockIdx.x;
  const unsigned int* h = hist + (size_t)b * HB * NBINS;
  for (int bin = threadIdx.x; bin < NBINS; bin += 256) {
    unsigned int s = 0;
    for (int k = 0; k < HB; ++k) s += h[(size_t)k * NBINS + bin];
    ch[bin] = s;
  }
  __syncthreads();
  unsigned int s = 0;
  int g0 = threadIdx.x * GR;
  for (int i = 0; i < GR; ++i) s += ch[g0 + i];
  gsum[threadIdx.x] = s;
  __syncthreads();
  if (threadIdx.x == 0) {
    unsigned int acc = 0;
    int g = 255;
    for (; g > 0; --g) {
      if (acc + gsum[g] >= (unsigned)KSEL) break;
      acc += gsum[g];
    }
    int t = g * GR;
    for (int bin = g * GR + GR - 1; bin >= g * GR; --bin) {
      acc += ch[bin];
      if (acc >= (unsigned)KSEL) { t = bin; break; }
    }
    tsel[b] = t;
  }
}

// ---------------- 3. compact candidates ----------------
__global__ __launch_bounds__(256) void compact_kernel(const float2* __restrict__ probs,
                                                      const int* __restrict__ tsel,
                                                      int* __restrict__ cnt,
                                                      ull* __restrict__ keys) {
  __shared__ int lcnt, lbase;
  __shared__ ull lbuf[2048];
  int b = blockIdx.y;
  int t = tsel[b];
  if (threadIdx.x == 0) lcnt = 0;
  __syncthreads();
  const float2* p = probs + (size_t)b * NA;
  for (int a = blockIdx.x * blockDim.x + threadIdx.x; a < NA; a += gridDim.x * blockDim.x) {
    float s = p[a].y;
    if (score_bin(s) >= t) {
      int pos = atomicAdd(&lcnt, 1);
      unsigned int ib = ~__float_as_uint(s);
      lbuf[pos] = ((ull)ib << 32) | (unsigned int)a;
    }
  }
  __syncthreads();
  if (threadIdx.x == 0) lbase = atomicAdd(&cnt[b * 16], lcnt);
  __syncthreads();
  int n = lcnt, base = lbase;
  ull* kb = keys + (size_t)b * CAP;
  for (int i = threadIdx.x; i < n; i += 256) {
    int pos = base + i;
    if (pos < CAP) kb[pos] = lbuf[i];
  }
}

// ---------------- 4. fused rank-by-counting + scatter + box decode ----------------
// Single pass: thread owns key i, counts #{j: key_j < key_i} over the full padded
// stream (pad = 0xFF.. = +inf, never counted), then decodes+scatters directly.
// No atomics, no rank array, no separate scatter launch.
__global__ __launch_bounds__(256) void rankscatter_kernel(const float4* __restrict__ anchors4,
                                                          const float4* __restrict__ bbox4,
                                                          const int* __restrict__ cnt,
                                                          const ull* __restrict__ keys,
                                                          float4* __restrict__ boxes4) {
#pragma clang fp contract(off)
  int b = blockIdx.y;
  int n = cnt[b * 16];
  if (n > CAP) n = CAP;
  int i = blockIdx.x * 256 + threadIdx.x;
  if (i >= n) return;
  const ull* kb = keys + (size_t)b * CAP;
  ull my = kb[i];
  int n16 = (n + 15) & ~15;
  unsigned int r = 0;
  for (int j = 0; j < n16; j += 16) {
#pragma unroll
    for (int t = 0; t < 16; ++t) {
      r += (kb[j + t] < my) ? 1u : 0u;
    }
  }
  if (r >= (unsigned)KSEL) return;
  int a = (int)(unsigned int)(my & 0xffffffffull);
  float4 anc = anchors4[(size_t)b * NA + a];
  float4 d   = bbox4[(size_t)b * NA + a];
  float h = anc.z - anc.x;
  float w = anc.w - anc.y;
  float dy = d.x * 0.1f, dx = d.y * 0.1f, dh = d.z * 0.2f, dw = d.w * 0.2f;
  float cy = (anc.x + (0.5f * h)) + (dy * h);
  float cx = (anc.y + (0.5f * w)) + (dx * w);
  float h2 = h * expf(dh);
  float w2 = w * expf(dw);
  float y1 = cy - 0.5f * h2;
  float x1 = cx - 0.5f * w2;
  float y2 = y1 + h2;
  float x2 = x1 + w2;
  y1 = fminf(fmaxf(y1, 0.f), 1.f);
  x1 = fminf(fmaxf(x1, 0.f), 1.f);
  y2 = fminf(fmaxf(y2, 0.f), 1.f);
  x2 = fminf(fmaxf(x2, 0.f), 1.f);
  boxes4[(size_t)b * KSEL + r] = make_float4(y1, x1, y2, x2);
}

// ---------------- 5. suppression mask: 2 rows/thread (round-22 proven, 117us) ----------------
// diagT written DIRECTLY in column form via ballot transpose:
// colT[l] bit r == "row i0+r suppresses row i0+l". superT stays row-form.
__global__ __launch_bounds__(256) void mask_kernel(const float4* __restrict__ boxes4,
                                                   ull* __restrict__ mask,
                                                   ull* __restrict__ diagT,
                                                   ull* __restrict__ superT) {
#pragma clang fp contract(off)
  int cx = blockIdx.x, rb2 = blockIdx.y, b = blockIdx.z;
  int w0 = 2 * rb2;
  int cb0 = w0 + 4 * cx;
  if (cb0 >= NWP) return;
  __shared__ float4 colbox[4][64];
  __shared__ float  colca[4][64];
  __shared__ ull wtile[128][5];
  int tid = threadIdx.x, wv = tid >> 6, l = tid & 63;
  int cb = cb0 + wv;
  int rA = rb2 * 128 + l, rB = rA + 64;
  float4 zero = make_float4(0.f, 0.f, 0.f, 0.f);
  float4 boxA = (rA < KSEL) ? boxes4[(size_t)b * KSEL + rA] : zero;
  float4 boxB = (rB < KSEL) ? boxes4[(size_t)b * KSEL + rB] : zero;
  float areaA = (boxA.z - boxA.x) * (boxA.w - boxA.y);
  float areaB = (boxB.z - boxB.x) * (boxB.w - boxB.y);
  int c = cb * 64 + l;
  float4 cload = (cb < NB && c < KSEL) ? boxes4[(size_t)b * KSEL + c] : zero;
  colbox[wv][l] = cload;
  colca[wv][l] = (cload.z - cload.x) * (cload.w - cload.y);
  __syncthreads();
  ull bitsA = 0ull, bitsB = 0ull;
  if (cb < NB) {
#pragma unroll
    for (int u = 0; u < 64; ++u) {
      float4 cbx = colbox[wv][u];
      float ca = colca[wv][u];
      {
        float ih = fmaxf(fminf(boxA.z, cbx.z) - fmaxf(boxA.x, cbx.x), 0.f);
        float iw = fmaxf(fminf(boxA.w, cbx.w) - fmaxf(boxA.y, cbx.y), 0.f);
        float inter = ih * iw;
        float uni = (areaA + ca) - inter;
        float d = fmaf(-0.7f, uni, inter);
        float tt = 6e-7f * uni;
        bool keep;
        if (__builtin_fabsf(d) <= tt) keep = (inter / uni) > 0.7f;
        else keep = d > 0.f;
        if (keep) bitsA |= (1ull << u);
      }
      {
        float ih = fmaxf(fminf(boxB.z, cbx.z) - fmaxf(boxB.x, cbx.x), 0.f);
        float iw = fmaxf(fminf(boxB.w, cbx.w) - fmaxf(boxB.y, cbx.y), 0.f);
        float inter = ih * iw;
        float uni = (areaB + ca) - inter;
        float d = fmaf(-0.7f, uni, inter);
        float tt = 6e-7f * uni;
        bool keep;
        if (__builtin_fabsf(d) <= tt) keep = (inter / uni) > 0.7f;
        else keep = d > 0.f;
        if (keep) bitsB |= (1ull << u);
      }
    }
    if (cb == w0) {
      bitsA &= (l == 63) ? 0ull : (~0ull << (l + 1)); // only cc > row suppress
      ull colT = 0ull;
#pragma unroll
      for (int k = 0; k < 64; ++k) {
        ull bk = __ballot(((bitsA >> k) & 1ull) != 0ull);
        if (l == k) colT = bk;
      }
      diagT[((size_t)b * NBLK + w0) * 64 + l] = colT;
    }
    if (cb == w0 + 1) {
      superT[((size_t)b * NBLK + w0) * 64 + l] = bitsA;  // word w0+1 of block-w0 rows (row form)
      bitsB &= (l == 63) ? 0ull : (~0ull << (l + 1));
      ull colT = 0ull;
#pragma unroll
      for (int k = 0; k < 64; ++k) {
        ull bk = __ballot(((bitsB >> k) & 1ull) != 0ull);
        if (l == k) colT = bk;
      }
      diagT[((size_t)b * NBLK + w0 + 1) * 64 + l] = colT;
    }
    if (cb == w0 + 2) {
      superT[((size_t)b * NBLK + w0 + 1) * 64 + l] = bitsB; // word w0+2 of block-(w0+1) rows
    }
  }
  wtile[l][wv] = bitsA;
  wtile[l + 64][wv] = bitsB;
  __syncthreads();
  int base_row = rb2 * 128;
#pragma unroll
  for (int pass = 0; pass < 2; ++pass) {
    int idx = pass * 256 + tid;
    int rr = idx >> 2, w = idx & 3;
    int row = base_row + rr;
    if (row < KSEL && cb0 + w < NWP)
      mask[((size_t)b * KSEL + row) * NWP + cb0 + w] = wtile[rr][w];
  }
}

// ---------------- 6. scan: ballot decision + urgent superdiag + concurrent lazy OR ----------------
__global__ __launch_bounds__(256, 1) void scan_kernel(const float4* __restrict__ boxes4,
                                                      const ull* __restrict__ mask,
                                                      const ull* __restrict__ diagT,
                                                      const ull* __restrict__ superT,
                                                      float4* __restrict__ out4) {
  __shared__ ull ldiagT[NBLK * 64];  // column form
  __shared__ ull lsuper[NBLK * 64];  // row form
  __shared__ ull S[96];
  __shared__ ull S_urg;
  __shared__ int klist[2][64];
  __shared__ int skeep[1024];
  __shared__ int s_kept, s_done, s_klen[2];
  int b = blockIdx.x;
  int tid = threadIdx.x;
  int lane = tid & 63;
  const ull* mb = mask + (size_t)b * KSEL * NWP;

  const ull* dt = diagT + (size_t)b * NBLK * 64;
  const ull* st = superT + (size_t)b * NBLK * 64;
  for (int i = tid; i < NBLK * 64; i += 256) { ldiagT[i] = dt[i]; lsuper[i] = st[i]; }
  if (tid < 96) S[tid] = 0ull;
  if (tid == 0) { s_kept = 0; s_done = 0; s_klen[0] = 0; s_klen[1] = 0; S_urg = 0ull; }
  __syncthreads();

  for (int n = 0; n < NBLK; ++n) {
    if (tid < 64) {
      ull Sn = S[n] | S_urg;
      int i0 = n * 64;
      ull colT = ldiagT[i0 + lane];
      ull sd = (n + 1 < NBLK) ? lsuper[i0 + lane] : 0ull;
      int nval = KSEL - i0;
      ull valid = (nval >= 64) ? ~0ull : ((1ull << nval) - 1ull);
      ull A = ~Sn & valid;
      ull K = 0ull;
      int kept = s_kept;
      int done = 0;
      while (A) {
        int u = __builtin_ctzll(A);
        ++kept;
        K |= (1ull << u);
        if (kept >= PROP) { done = 1; break; }
        ull sup = __ballot(((colT >> u) & 1ull) != 0ull);
        A &= ~(sup | (1ull << u));
      }
      int klen = __builtin_popcountll(K);
      int kbase = kept - klen;
      if ((K >> lane) & 1ull) {
        int rank = __builtin_popcountll(K & ((1ull << lane) - 1ull));
        skeep[kbase + rank] = i0 + lane;
        klist[n & 1][rank] = i0 + lane;
      }
      int klp = (klen + 7) & ~7;
      if (klen > 0 && lane >= klen && lane < klp)
        klist[n & 1][lane] = i0 + __builtin_ctzll(K);
      unsigned ulo = (unsigned)sd, uhi = (unsigned)(sd >> 32);
      if (!((K >> lane) & 1ull)) { ulo = 0u; uhi = 0u; }
#pragma unroll
      for (int m = 1; m < 64; m <<= 1) {
        ulo |= (unsigned)__shfl_xor((int)ulo, m, 64);
        uhi |= (unsigned)__shfl_xor((int)uhi, m, 64);
      }
      if (lane == 0) {
        s_klen[n & 1] = klen;
        S_urg = (ull)ulo | ((ull)uhi << 32);
        s_kept = kept;
        if (done || n == NBLK - 1) s_done = 1;
      }
    } else {
      int prev = (n & 1) ^ 1;
      int kl = s_klen[prev];
      int w = n + 1 + (tid - 64);
      if (kl > 0 && w < NB) {
        const int* kp = klist[prev];
        ull acc = 0ull;
        int klp = (kl + 7) & ~7;
        for (int ri = 0; ri < klp; ri += 8) {
#pragma unroll
          for (int t2 = 0; t2 < 8; ++t2)
            acc |= mb[(size_t)kp[ri + t2] * NWP + w];
        }
        S[w] |= acc;
      }
    }
    __syncthreads();
    if (s_done) break;
  }

  int fin = s_kept;
  if (fin > PROP) fin = PROP;
  for (int r2 = tid; r2 < PROP; r2 += 256) {
    float4 v = make_float4(0.f, 0.f, 0.f, 0.f);
    if (r2 < fin) v = boxes4[(size_t)b * KSEL + skeep[r2]];
    out4[(size_t)b * PROP + r2] = v;
  }
}

// ---------------- launch (6 dispatches, no memsets) ----------------
extern "C" void kernel_launch(void* const* d_in, const int* in_sizes, int n_in,
                              void* d_out, int out_size, void* d_ws, size_t ws_size,
                              hipStream_t stream) {
  const float2* probs   = (const float2*)d_in[0];
  const float4* bbox4   = (const float4*)d_in[1];
  const float4* anchors4= (const float4*)d_in[2];
  float4* out4 = (float4*)d_out;
  char* ws = (char*)d_ws;

  int* cnt           = (int*)(ws + OFF_CNT);
  int* tsel          = (int*)(ws + OFF_TSEL);
  float4* boxes4     = (float4*)(ws + OFF_BOXES);
  ull* maskw         = (ull*)(ws + OFF_MASK);
  ull* diagT         = (ull*)(ws + OFF_DIAG);
  ull* superT        = (ull*)(ws + OFF_SUP);
  ull* keys          = (ull*)(ws + OFF_KEYS);
  unsigned int* hist = (unsigned int*)(ws + OFF_HIST);

  hipLaunchKernelGGL(hist_kernel,        dim3(HB, BATCH),      dim3(256), 0, stream, probs, hist, cnt, keys);
  hipLaunchKernelGGL(thresh_kernel,      dim3(BATCH),          dim3(256), 0, stream, hist, tsel);
  hipLaunchKernelGGL(compact_kernel,     dim3(128, BATCH),     dim3(256), 0, stream, probs, tsel, cnt, keys);
  hipLaunchKernelGGL(rankscatter_kernel, dim3(32, BATCH),      dim3(256), 0, stream, anchors4, bbox4, cnt, keys, boxes4);
  hipLaunchKernelGGL(mask_kernel,        dim3(24, NBLK2, BATCH), dim3(256), 0, stream, boxes4, maskw, diagT, superT);
  hipLaunchKernelGGL(scan_kernel,        dim3(BATCH),          dim3(256), 0, stream, boxes4, maskw, diagT, superT, out4);
}

// Round 25
// 331.181 us; speedup vs baseline: 1.2178x; 1.1811x over previous
//
#include <hip/hip_runtime.h>
#include <hip/hip_bf16.h>

typedef unsigned long long ull;

// ---------------- problem constants ----------------
constexpr int BATCH = 8;
constexpr int NA    = 261888;
constexpr int KSEL  = 6000;          // PRE_NMS_LIMIT
constexpr int PROP  = 1000;          // PROPOSAL_COUNT
constexpr int CAP   = 8192;          // candidate capacity
constexpr int NBINS = 8192;          // histogram bins
constexpr int HB    = 16;            // private histogram blocks per batch
constexpr int NB    = (KSEL + 63) / 64;   // 94 mask words per row
constexpr int NWP   = 94;            // words per row (752B rows)
constexpr int NBLK  = 94;            // row-blocks
constexpr int NBLK2 = 47;            // 128-row pair-blocks (mask kernel)

// workspace layout (bytes). keys/hist alias the mask head (disjoint liveness).
constexpr size_t OFF_CNT   = 0;                       // 512 (128 ints)
constexpr size_t OFF_TSEL  = 512;                     // 32
constexpr size_t OFF_BOXES = 544;                     // 8*6000*16 = 768000
constexpr size_t OFF_MASK  = 769024;                  // 8*6000*94*8 = 36096000
constexpr size_t OFF_DIAG  = OFF_MASK + 36096000;     // 8*94*64*8 = 385024
constexpr size_t OFF_SUP   = OFF_DIAG + 385024;       // 8*94*64*8 = 385024
constexpr size_t OFF_KEYS  = OFF_MASK;                // 524288 (aliased)
constexpr size_t OFF_HIST  = OFF_MASK + 2097152;      // 4MB (aliased)
// total = 37,635,072 B

__device__ __forceinline__ int score_bin(float s) {
  int b = (int)(s * (float)NBINS);
  if (b < 0) b = 0;
  if (b > NBINS - 1) b = NBINS - 1;
  return b;
}

// ---------------- 1. histogram (+ workspace init: cnt zero, keys 0xFF pad) ----------------
__global__ __launch_bounds__(256) void hist_kernel(const float2* __restrict__ probs,
                                                   unsigned int* __restrict__ hist,
                                                   int* __restrict__ cnt,
                                                   ull* __restrict__ keys) {
  __shared__ unsigned int lh[NBINS];
  for (int i = threadIdx.x; i < NBINS; i += 256) lh[i] = 0u;
  int fb = blockIdx.y * HB + blockIdx.x;   // 0..127
  if (threadIdx.x == 0) cnt[fb] = 0;
  {
    ull* kp = keys + (size_t)fb * 512;     // 128 blocks x 512 = whole keys region
    for (int i = threadIdx.x; i < 512; i += 256) kp[i] = ~0ull;
  }
  __syncthreads();
  int b = blockIdx.y;
  const float2* p = probs + (size_t)b * NA;
  for (int a = blockIdx.x * 256 + threadIdx.x; a < NA; a += HB * 256) {
    atomicAdd(&lh[score_bin(p[a].y)], 1u);
  }
  __syncthreads();
  unsigned int* gh = hist + ((size_t)b * HB + blockIdx.x) * NBINS;
  for (int i = threadIdx.x; i < NBINS; i += 256) gh[i] = lh[i];
}

// ---------------- 2. threshold bin select ----------------
__global__ __launch_bounds__(256) void thresh_kernel(const unsigned int* __restrict__ hist,
                                                     int* __restrict__ tsel) {
  constexpr int GR = NBINS / 256;
  __shared__ unsigned int ch[NBINS];
  __shared__ unsigned int gsum[256];
  int b = blockIdx.x;
  const unsigned int* h = hist + (size_t)b * HB * NBINS;
  for (int bin = threadIdx.x; bin < NBINS; bin += 256) {
    unsigned int s = 0;
    for (int k = 0; k < HB; ++k) s += h[(size_t)k * NBINS + bin];
    ch[bin] = s;
  }
  __syncthreads();
  unsigned int s = 0;
  int g0 = threadIdx.x * GR;
  for (int i = 0; i < GR; ++i) s += ch[g0 + i];
  gsum[threadIdx.x] = s;
  __syncthreads();
  if (threadIdx.x == 0) {
    unsigned int acc = 0;
    int g = 255;
    for (; g > 0; --g) {
      if (acc + gsum[g] >= (unsigned)KSEL) break;
      acc += gsum[g];
    }
    int t = g * GR;
    for (int bin = g * GR + GR - 1; bin >= g * GR; --bin) {
      acc += ch[bin];
      if (acc >= (unsigned)KSEL) { t = bin; break; }
    }
    tsel[b] = t;
  }
}

// ---------------- 3. compact candidates ----------------
__global__ __launch_bounds__(256) void compact_kernel(const float2* __restrict__ probs,
                                                      const int* __restrict__ tsel,
                                                      int* __restrict__ cnt,
                                                      ull* __restrict__ keys) {
  __shared__ int lcnt, lbase;
  __shared__ ull lbuf[2048];
  int b = blockIdx.y;
  int t = tsel[b];
  if (threadIdx.x == 0) lcnt = 0;
  __syncthreads();
  const float2* p = probs + (size_t)b * NA;
  for (int a = blockIdx.x * blockDim.x + threadIdx.x; a < NA; a += gridDim.x * blockDim.x) {
    float s = p[a].y;
    if (score_bin(s) >= t) {
      int pos = atomicAdd(&lcnt, 1);
      unsigned int ib = ~__float_as_uint(s);
      lbuf[pos] = ((ull)ib << 32) | (unsigned int)a;
    }
  }
  __syncthreads();
  if (threadIdx.x == 0) lbase = atomicAdd(&cnt[b * 16], lcnt);
  __syncthreads();
  int n = lcnt, base = lbase;
  ull* kb = keys + (size_t)b * CAP;
  for (int i = threadIdx.x; i < n; i += 256) {
    int pos = base + i;
    if (pos < CAP) kb[pos] = lbuf[i];
  }
}

// ---------------- 4. fused rank+scatter, LDS-tiled key stream ----------------
// Per block: stage the stream in 1024-key LDS tiles (coalesced); each thread compares
// its key against the tile via uniform broadcast reads (no conflicts, no L2 latency).
// Pads (0xFF..) never compare-less. All threads join the coop loads (barrier-safe).
__global__ __launch_bounds__(256) void rankscatter_kernel(const float4* __restrict__ anchors4,
                                                          const float4* __restrict__ bbox4,
                                                          const int* __restrict__ cnt,
                                                          const ull* __restrict__ keys,
                                                          float4* __restrict__ boxes4) {
#pragma clang fp contract(off)
  __shared__ ull tile[1024];
  int b = blockIdx.y;
  int n = cnt[b * 16];
  if (n > CAP) n = CAP;
  int i = blockIdx.x * 256 + threadIdx.x;
  const ull* kb = keys + (size_t)b * CAP;
  ull my = (i < CAP) ? kb[(i < n) ? i : 0] : ~0ull;
  if (i >= n) my = ~0ull;
  unsigned int r = 0;
  int ntile = (n + 1023) & ~1023;          // <= CAP; pad region is 0xFF-initialized
  for (int j0 = 0; j0 < ntile; j0 += 1024) {
    for (int k = threadIdx.x; k < 1024; k += 256) tile[k] = kb[j0 + k];
    __syncthreads();
#pragma unroll 16
    for (int k = 0; k < 1024; ++k) r += (tile[k] < my) ? 1u : 0u;
    __syncthreads();
  }
  if (i >= n || r >= (unsigned)KSEL) return;
  int a = (int)(unsigned int)(my & 0xffffffffull);
  float4 anc = anchors4[(size_t)b * NA + a];
  float4 d   = bbox4[(size_t)b * NA + a];
  float h = anc.z - anc.x;
  float w = anc.w - anc.y;
  float dy = d.x * 0.1f, dx = d.y * 0.1f, dh = d.z * 0.2f, dw = d.w * 0.2f;
  float cy = (anc.x + (0.5f * h)) + (dy * h);
  float cx = (anc.y + (0.5f * w)) + (dx * w);
  float h2 = h * expf(dh);
  float w2 = w * expf(dw);
  float y1 = cy - 0.5f * h2;
  float x1 = cx - 0.5f * w2;
  float y2 = y1 + h2;
  float x2 = x1 + w2;
  y1 = fminf(fmaxf(y1, 0.f), 1.f);
  x1 = fminf(fmaxf(x1, 0.f), 1.f);
  y2 = fminf(fmaxf(y2, 0.f), 1.f);
  x2 = fminf(fmaxf(x2, 0.f), 1.f);
  boxes4[(size_t)b * KSEL + r] = make_float4(y1, x1, y2, x2);
}

// ---------------- 5. suppression mask: 2 rows/thread (round-22 proven, 117us) ----------------
__global__ __launch_bounds__(256) void mask_kernel(const float4* __restrict__ boxes4,
                                                   ull* __restrict__ mask,
                                                   ull* __restrict__ diagT,
                                                   ull* __restrict__ superT) {
#pragma clang fp contract(off)
  int cx = blockIdx.x, rb2 = blockIdx.y, b = blockIdx.z;
  int w0 = 2 * rb2;
  int cb0 = w0 + 4 * cx;
  if (cb0 >= NWP) return;
  __shared__ float4 colbox[4][64];
  __shared__ float  colca[4][64];
  __shared__ ull wtile[128][5];
  int tid = threadIdx.x, wv = tid >> 6, l = tid & 63;
  int cb = cb0 + wv;
  int rA = rb2 * 128 + l, rB = rA + 64;
  float4 zero = make_float4(0.f, 0.f, 0.f, 0.f);
  float4 boxA = (rA < KSEL) ? boxes4[(size_t)b * KSEL + rA] : zero;
  float4 boxB = (rB < KSEL) ? boxes4[(size_t)b * KSEL + rB] : zero;
  float areaA = (boxA.z - boxA.x) * (boxA.w - boxA.y);
  float areaB = (boxB.z - boxB.x) * (boxB.w - boxB.y);
  int c = cb * 64 + l;
  float4 cload = (cb < NB && c < KSEL) ? boxes4[(size_t)b * KSEL + c] : zero;
  colbox[wv][l] = cload;
  colca[wv][l] = (cload.z - cload.x) * (cload.w - cload.y);
  __syncthreads();
  ull bitsA = 0ull, bitsB = 0ull;
  if (cb < NB) {
#pragma unroll
    for (int u = 0; u < 64; ++u) {
      float4 cbx = colbox[wv][u];
      float ca = colca[wv][u];
      {
        float ih = fmaxf(fminf(boxA.z, cbx.z) - fmaxf(boxA.x, cbx.x), 0.f);
        float iw = fmaxf(fminf(boxA.w, cbx.w) - fmaxf(boxA.y, cbx.y), 0.f);
        float inter = ih * iw;
        float uni = (areaA + ca) - inter;
        float d = fmaf(-0.7f, uni, inter);
        float tt = 6e-7f * uni;
        bool keep;
        if (__builtin_fabsf(d) <= tt) keep = (inter / uni) > 0.7f;
        else keep = d > 0.f;
        if (keep) bitsA |= (1ull << u);
      }
      {
        float ih = fmaxf(fminf(boxB.z, cbx.z) - fmaxf(boxB.x, cbx.x), 0.f);
        float iw = fmaxf(fminf(boxB.w, cbx.w) - fmaxf(boxB.y, cbx.y), 0.f);
        float inter = ih * iw;
        float uni = (areaB + ca) - inter;
        float d = fmaf(-0.7f, uni, inter);
        float tt = 6e-7f * uni;
        bool keep;
        if (__builtin_fabsf(d) <= tt) keep = (inter / uni) > 0.7f;
        else keep = d > 0.f;
        if (keep) bitsB |= (1ull << u);
      }
    }
    if (cb == w0) {
      bitsA &= (l == 63) ? 0ull : (~0ull << (l + 1)); // only cc > row suppress
      ull colT = 0ull;
#pragma unroll
      for (int k = 0; k < 64; ++k) {
        ull bk = __ballot(((bitsA >> k) & 1ull) != 0ull);
        if (l == k) colT = bk;
      }
      diagT[((size_t)b * NBLK + w0) * 64 + l] = colT;
    }
    if (cb == w0 + 1) {
      superT[((size_t)b * NBLK + w0) * 64 + l] = bitsA;  // word w0+1 of block-w0 rows (row form)
      bitsB &= (l == 63) ? 0ull : (~0ull << (l + 1));
      ull colT = 0ull;
#pragma unroll
      for (int k = 0; k < 64; ++k) {
        ull bk = __ballot(((bitsB >> k) & 1ull) != 0ull);
        if (l == k) colT = bk;
      }
      diagT[((size_t)b * NBLK + w0 + 1) * 64 + l] = colT;
    }
    if (cb == w0 + 2) {
      superT[((size_t)b * NBLK + w0 + 1) * 64 + l] = bitsB; // word w0+2 of block-(w0+1) rows
    }
  }
  wtile[l][wv] = bitsA;
  wtile[l + 64][wv] = bitsB;
  __syncthreads();
  int base_row = rb2 * 128;
#pragma unroll
  for (int pass = 0; pass < 2; ++pass) {
    int idx = pass * 256 + tid;
    int rr = idx >> 2, w = idx & 3;
    int row = base_row + rr;
    if (row < KSEL && cb0 + w < NWP)
      mask[((size_t)b * KSEL + row) * NWP + cb0 + w] = wtile[rr][w];
  }
}

// ---------------- 6. scan: ballot decision + urgent superdiag + concurrent lazy OR ----------------
__global__ __launch_bounds__(256, 1) void scan_kernel(const float4* __restrict__ boxes4,
                                                      const ull* __restrict__ mask,
                                                      const ull* __restrict__ diagT,
                                                      const ull* __restrict__ superT,
                                                      float4* __restrict__ out4) {
  __shared__ ull ldiagT[NBLK * 64];  // column form
  __shared__ ull lsuper[NBLK * 64];  // row form
  __shared__ ull S[96];
  __shared__ ull S_urg;
  __shared__ int klist[2][64];
  __shared__ int skeep[1024];
  __shared__ int s_kept, s_done, s_klen[2];
  int b = blockIdx.x;
  int tid = threadIdx.x;
  int lane = tid & 63;
  const ull* mb = mask + (size_t)b * KSEL * NWP;

  const ull* dt = diagT + (size_t)b * NBLK * 64;
  const ull* st = superT + (size_t)b * NBLK * 64;
  for (int i = tid; i < NBLK * 64; i += 256) { ldiagT[i] = dt[i]; lsuper[i] = st[i]; }
  if (tid < 96) S[tid] = 0ull;
  if (tid == 0) { s_kept = 0; s_done = 0; s_klen[0] = 0; s_klen[1] = 0; S_urg = 0ull; }
  __syncthreads();

  for (int n = 0; n < NBLK; ++n) {
    if (tid < 64) {
      ull Sn = S[n] | S_urg;
      int i0 = n * 64;
      ull colT = ldiagT[i0 + lane];
      ull sd = (n + 1 < NBLK) ? lsuper[i0 + lane] : 0ull;
      int nval = KSEL - i0;
      ull valid = (nval >= 64) ? ~0ull : ((1ull << nval) - 1ull);
      ull A = ~Sn & valid;
      ull K = 0ull;
      int kept = s_kept;
      int done = 0;
      while (A) {
        int u = __builtin_ctzll(A);
        ++kept;
        K |= (1ull << u);
        if (kept >= PROP) { done = 1; break; }
        ull sup = __ballot(((colT >> u) & 1ull) != 0ull);
        A &= ~(sup | (1ull << u));
      }
      int klen = __builtin_popcountll(K);
      int kbase = kept - klen;
      if ((K >> lane) & 1ull) {
        int rank = __builtin_popcountll(K & ((1ull << lane) - 1ull));
        skeep[kbase + rank] = i0 + lane;
        klist[n & 1][rank] = i0 + lane;
      }
      int klp = (klen + 7) & ~7;
      if (klen > 0 && lane >= klen && lane < klp)
        klist[n & 1][lane] = i0 + __builtin_ctzll(K);
      unsigned ulo = (unsigned)sd, uhi = (unsigned)(sd >> 32);
      if (!((K >> lane) & 1ull)) { ulo = 0u; uhi = 0u; }
#pragma unroll
      for (int m = 1; m < 64; m <<= 1) {
        ulo |= (unsigned)__shfl_xor((int)ulo, m, 64);
        uhi |= (unsigned)__shfl_xor((int)uhi, m, 64);
      }
      if (lane == 0) {
        s_klen[n & 1] = klen;
        S_urg = (ull)ulo | ((ull)uhi << 32);
        s_kept = kept;
        if (done || n == NBLK - 1) s_done = 1;
      }
    } else {
      int prev = (n & 1) ^ 1;
      int kl = s_klen[prev];
      int w = n + 1 + (tid - 64);
      if (kl > 0 && w < NB) {
        const int* kp = klist[prev];
        ull acc = 0ull;
        int klp = (kl + 7) & ~7;
        for (int ri = 0; ri < klp; ri += 8) {
#pragma unroll
          for (int t2 = 0; t2 < 8; ++t2)
            acc |= mb[(size_t)kp[ri + t2] * NWP + w];
        }
        S[w] |= acc;
      }
    }
    __syncthreads();
    if (s_done) break;
  }

  int fin = s_kept;
  if (fin > PROP) fin = PROP;
  for (int r2 = tid; r2 < PROP; r2 += 256) {
    float4 v = make_float4(0.f, 0.f, 0.f, 0.f);
    if (r2 < fin) v = boxes4[(size_t)b * KSEL + skeep[r2]];
    out4[(size_t)b * PROP + r2] = v;
  }
}

// ---------------- launch (6 dispatches, no memsets) ----------------
extern "C" void kernel_launch(void* const* d_in, const int* in_sizes, int n_in,
                              void* d_out, int out_size, void* d_ws, size_t ws_size,
                              hipStream_t stream) {
  const float2* probs   = (const float2*)d_in[0];
  const float4* bbox4   = (const float4*)d_in[1];
  const float4* anchors4= (const float4*)d_in[2];
  float4* out4 = (float4*)d_out;
  char* ws = (char*)d_ws;

  int* cnt           = (int*)(ws + OFF_CNT);
  int* tsel          = (int*)(ws + OFF_TSEL);
  float4* boxes4     = (float4*)(ws + OFF_BOXES);
  ull* maskw         = (ull*)(ws + OFF_MASK);
  ull* diagT         = (ull*)(ws + OFF_DIAG);
  ull* superT        = (ull*)(ws + OFF_SUP);
  ull* keys          = (ull*)(ws + OFF_KEYS);
  unsigned int* hist = (unsigned int*)(ws + OFF_HIST);

  hipLaunchKernelGGL(hist_kernel,        dim3(HB, BATCH),      dim3(256), 0, stream, probs, hist, cnt, keys);
  hipLaunchKernelGGL(thresh_kernel,      dim3(BATCH),          dim3(256), 0, stream, hist, tsel);
  hipLaunchKernelGGL(compact_kernel,     dim3(128, BATCH),     dim3(256), 0, stream, probs, tsel, cnt, keys);
  hipLaunchKernelGGL(rankscatter_kernel, dim3(32, BATCH),      dim3(256), 0, stream, anchors4, bbox4, cnt, keys, boxes4);
  hipLaunchKernelGGL(mask_kernel,        dim3(24, NBLK2, BATCH), dim3(256), 0, stream, boxes4, maskw, diagT, superT);
  hipLaunchKernelGGL(scan_kernel,        dim3(BATCH),          dim3(256), 0, stream, boxes4, maskw, diagT, superT, out4);
}